// Round 1
// baseline (432.715 us; speedup 1.0000x reference)
//
#include <hip/hip_runtime.h>
#include <hip/hip_bf16.h>

// g[b,h,w] = (1/N) * sum_n conj(H[n,h,w]) * (H[n,h,w]*x[b,h,w] - y[b,n,h,w])
//          = x[b,h,w] * (1/N)*sum_n |H[n,h,w]|^2  -  (1/N)*sum_n conj(H[n,h,w])*y[b,n,h,w]
//
// Layouts (contiguous, complex interleaved in last dim):
//   f_ipt : [B, H, W, 2]      -> X4 viewed as [B][P] float4  (P = H*W*2/4, 2 pixels per float4)
//   f_y   : [B, N, H, W, 2]   -> Y4 viewed as [B][N][P] float4
//   Hreal : [N, H, W, 2]      -> H4 viewed as [N][P] float4
//   out g : [B, H, W, 2]      -> O4 viewed as [B][P] float4
//
// One thread per float4 group p; stream over n reading H once (shared across
// both batch elements in registers). Pure one-pass HBM-bound kernel.

__global__ void __launch_bounds__(256) idt_fused_kernel(
    const float4* __restrict__ H4,   // [N][P]
    const float4* __restrict__ Y4,   // [B=2][N][P]
    const float4* __restrict__ X4,   // [B=2][P]
    float4* __restrict__ O4,         // [B=2][P]
    const int* __restrict__ nbf,
    int N, int P)
{
    int p = blockIdx.x * blockDim.x + threadIdx.x;
    if (p >= P) return;

    // accumulators: |H|^2 for pixel0/pixel1, conj(H)*y for (b=0,1)x(pix0,pix1)
    float s0 = 0.f, s1 = 0.f;
    float a00r = 0.f, a00i = 0.f, a01r = 0.f, a01i = 0.f;  // b=0
    float a10r = 0.f, a10i = 0.f, a11r = 0.f, a11i = 0.f;  // b=1

    const float4* hp = H4 + p;
    const float4* y0 = Y4 + p;                       // b=0
    const float4* y1 = Y4 + (size_t)N * P + p;       // b=1

    #pragma unroll 4
    for (int n = 0; n < N; ++n) {
        float4 hv = hp[(size_t)n * P];
        float4 v0 = y0[(size_t)n * P];
        float4 v1 = y1[(size_t)n * P];

        // |H|^2 (pixel 0: .x/.y, pixel 1: .z/.w)
        s0 += hv.x * hv.x + hv.y * hv.y;
        s1 += hv.z * hv.z + hv.w * hv.w;

        // conj(H) * y = (Hr*yr + Hi*yi) + i(Hr*yi - Hi*yr)
        a00r += hv.x * v0.x + hv.y * v0.y;
        a00i += hv.x * v0.y - hv.y * v0.x;
        a01r += hv.z * v0.z + hv.w * v0.w;
        a01i += hv.z * v0.w - hv.w * v0.z;

        a10r += hv.x * v1.x + hv.y * v1.y;
        a10i += hv.x * v1.y - hv.y * v1.x;
        a11r += hv.z * v1.z + hv.w * v1.w;
        a11i += hv.z * v1.w - hv.w * v1.z;
    }

    float inv = 1.0f / (float)nbf[0];

    float4 x0 = X4[p];
    float4 x1 = X4[(size_t)P + p];

    float4 o0, o1;
    o0.x = (x0.x * s0 - a00r) * inv;
    o0.y = (x0.y * s0 - a00i) * inv;
    o0.z = (x0.z * s1 - a01r) * inv;
    o0.w = (x0.w * s1 - a01i) * inv;

    o1.x = (x1.x * s0 - a10r) * inv;
    o1.y = (x1.y * s0 - a10i) * inv;
    o1.z = (x1.z * s1 - a11r) * inv;
    o1.w = (x1.w * s1 - a11i) * inv;

    O4[p] = o0;
    O4[(size_t)P + p] = o1;
}

extern "C" void kernel_launch(void* const* d_in, const int* in_sizes, int n_in,
                              void* d_out, int out_size, void* d_ws, size_t ws_size,
                              hipStream_t stream) {
    const float* f_ipt = (const float*)d_in[0];   // [B,H,W,2]
    const float* f_y   = (const float*)d_in[1];   // [B,N,H,W,2]
    const float* Hreal = (const float*)d_in[2];   // [N,H,W,2]
    const int*   nbf   = (const int*)d_in[3];     // scalar NBFkeep

    // Derive dims from sizes: B = f_y/Hreal, N = f_y/f_ipt, P = (H*W*2)/4
    const int B = in_sizes[1] / in_sizes[2];      // = 2
    const int N = in_sizes[1] / in_sizes[0];      // = 64
    const int P = in_sizes[0] / B / 4;            // = 131072

    dim3 block(256);
    dim3 grid((P + block.x - 1) / block.x);
    idt_fused_kernel<<<grid, block, 0, stream>>>(
        (const float4*)Hreal, (const float4*)f_y, (const float4*)f_ipt,
        (float4*)d_out, nbf, N, P);
}